// Round 5
// baseline (405.251 us; speedup 1.0000x reference)
//
#include <hip/hip_runtime.h>
#include <math.h>

#define EPSF 1e-8f
#define LAM 20.0f

typedef short short8 __attribute__((ext_vector_type(8)));
typedef float f32x4 __attribute__((ext_vector_type(4)));

__device__ __forceinline__ unsigned short f2bf(float x) {
  unsigned u = __float_as_uint(x);
  u += 0x7fffu + ((u >> 16) & 1u);
  return (unsigned short)(u >> 16);
}
__device__ __forceinline__ float bf2f(unsigned short h) {
  return __uint_as_float(((unsigned)h) << 16);
}

// ---------------------------------------------------------------------------
// Kernel 1: row norms + bf16 normalized copies.
// ---------------------------------------------------------------------------
__global__ __launch_bounds__(256) void norm_convert(
    const float* __restrict__ im, const float* __restrict__ s,
    float* __restrict__ nim, float* __restrict__ ns,
    unsigned short* __restrict__ imn, unsigned short* __restrict__ sn) {
  int row = blockIdx.x * 4 + (threadIdx.x >> 6);
  int lane = threadIdx.x & 63;
  const float* src;
  unsigned short* dst;
  float* ndst;
  if (row < 8192) {
    src = im + ((size_t)row << 9);
    dst = imn + ((size_t)row << 9);
    ndst = nim + row;
  } else {
    int r = row - 8192;
    src = s + ((size_t)r << 9);
    dst = sn + ((size_t)r << 9);
    ndst = ns + r;
  }
  float4 v0 = ((const float4*)src)[lane * 2];
  float4 v1 = ((const float4*)src)[lane * 2 + 1];
  float ss = 0.f;
  ss = fmaf(v0.x, v0.x, ss); ss = fmaf(v0.y, v0.y, ss);
  ss = fmaf(v0.z, v0.z, ss); ss = fmaf(v0.w, v0.w, ss);
  ss = fmaf(v1.x, v1.x, ss); ss = fmaf(v1.y, v1.y, ss);
  ss = fmaf(v1.z, v1.z, ss); ss = fmaf(v1.w, v1.w, ss);
#pragma unroll
  for (int o = 32; o; o >>= 1) ss += __shfl_xor(ss, o);
  float n = sqrtf(ss);
  if (lane == 0) *ndst = n;
  float ci = 1.0f / (n + EPSF);
  union { unsigned short us[8]; uint4 v; } p;
  p.us[0] = f2bf(v0.x * ci); p.us[1] = f2bf(v0.y * ci);
  p.us[2] = f2bf(v0.z * ci); p.us[3] = f2bf(v0.w * ci);
  p.us[4] = f2bf(v1.x * ci); p.us[5] = f2bf(v1.y * ci);
  p.us[6] = f2bf(v1.z * ci); p.us[7] = f2bf(v1.w * ci);
  ((uint4*)dst)[lane] = p.v;
}

// ---------------------------------------------------------------------------
// Kernel 2: bf16 Gram matrices via MFMA. One block per c. G = ctxn @ ctxn^T.
// ---------------------------------------------------------------------------
template <int LS>
__global__ __launch_bounds__(256, 2) void gram_mfma(
    const unsigned short* __restrict__ ctxn, unsigned short* __restrict__ Gbf) {
  constexpr int RW = (LS / 16) / 2;
  __shared__ __align__(16) char sm[LS * 272];
  const int c = blockIdx.x, t = threadIdx.x;
  const int w = t >> 6, lane = t & 63, m16 = lane & 15, grp = lane >> 4;
  const int rT0 = (w & 1) * RW, cT0 = (w >> 1) * RW;
  const unsigned short* base = ctxn + ((size_t)c * LS << 9);
  f32x4 g[RW][RW];
#pragma unroll
  for (int ri = 0; ri < RW; ri++)
#pragma unroll
    for (int ci = 0; ci < RW; ci++) g[ri][ci] = {0.f, 0.f, 0.f, 0.f};

  for (int ch = 0; ch < 4; ch++) {
    __syncthreads();
    for (int idx = t; idx < LS * 16; idx += 256) {
      int row = idx >> 4, u = idx & 15;
      *(uint4*)(sm + row * 272 + u * 16) =
          ((const uint4*)(base + ((size_t)row << 9) + (ch << 7)))[u];
    }
    __syncthreads();
#pragma unroll
    for (int kk = 0; kk < 4; kk++) {
      short8 a[RW], b[RW];
#pragma unroll
      for (int ri = 0; ri < RW; ri++)
        a[ri] = *(const short8*)(sm + ((rT0 + ri) * 16 + m16) * 272 + kk * 64 + grp * 16);
#pragma unroll
      for (int ci = 0; ci < RW; ci++)
        b[ci] = *(const short8*)(sm + ((cT0 + ci) * 16 + m16) * 272 + kk * 64 + grp * 16);
#pragma unroll
      for (int ri = 0; ri < RW; ri++)
#pragma unroll
        for (int ci = 0; ci < RW; ci++)
          g[ri][ci] = __builtin_amdgcn_mfma_f32_16x16x32_bf16(a[ri], b[ci], g[ri][ci], 0, 0, 0);
    }
  }
#pragma unroll
  for (int ri = 0; ri < RW; ri++)
#pragma unroll
    for (int ci = 0; ci < RW; ci++)
#pragma unroll
      for (int r = 0; r < 4; r++) {
        int s = (rT0 + ri) * 16 + grp * 4 + r;
        int sp = (cT0 + ci) * 16 + m16;
        Gbf[(size_t)c * LS * LS + s * LS + sp] = f2bf(g[ri][ci][r]);
      }
}

// ---------------------------------------------------------------------------
// Kernel 3: macro-tiled fused attention. Block = 128x128 tile spanning
// GC contexts x GQ queries.  i2t: <64,32,2,4>, t2i: <32,64,4,2>.
// S0/attn rows: bf16, 264-byte pitch (8B-aligned; 2 dwords mod 32 -> 2-way max
// on row-parallel b64 reads). All S0 accesses are <=8B granules.
// ---------------------------------------------------------------------------
template <int LS, int LQ, int GC, int GQ>
__global__ __launch_bounds__(256, 2) void attn_tile(
    const unsigned short* __restrict__ ctxn,  // (128,LS,512) bf16
    const unsigned short* __restrict__ qryn,  // (128,LQ,512) bf16
    const unsigned short* __restrict__ Gbf,   // (128,LS,LS) bf16
    const float* __restrict__ qnrm,           // 128*LQ raw query norms
    const float* __restrict__ cmask,          // (128,LS)
    float* __restrict__ sim) {
  static_assert(GC * LS == 128 && GQ * LQ == 128, "tile must be 128x128");
  constexpr int SROW = 144;                 // staging row stride (64 bf16 + pad)
  constexpr int BOFF = 128 * SROW;          // qry staging after ctx
  constexpr int S0P = 264;                  // S0/attn row pitch (bytes)
  constexpr int GOFF = 256 * SROW;          // 36864: G region
  constexpr int GST = LS * 2 + 16;          // G row stride bytes
  constexpr int FOFF = GOFF + 128 * GST;    // float scratch
  constexpr int NF = GQ * 128 + GC * 128 + 512 + 256;
  static_assert(127 * S0P + 256 <= 256 * SROW, "S0 overflows staging alias");
  __shared__ __align__(16) char sm[FOFF + NF * 4];
  float* rinvv = (float*)(sm + FOFF);       // [GQ][128]
  float* w12v = rinvv + GQ * 128;           // [GC][128]
  float* psum = w12v + GC * 128;            // [4][128] wn2 wave partials
  float* cmv = psum + 512;                  // [128]
  float* qnv = cmv + 128;                   // [128]

  const int bq = blockIdx.x, bc = blockIdx.y, t = threadIdx.x;
  const int w = t >> 6, lane = t & 63, m16 = lane & 15, grp = lane >> 4;

  auto soff = [](int n) { return n * S0P; };

  const unsigned short* aBase = ctxn + ((size_t)bc << 16);  // bc*128*512
  const unsigned short* bBase = qryn + ((size_t)bq << 16);

  // ---- preload G, cmask, qnorms (ordering covered by P1 barriers) ----
  if (t < 128) cmv[t] = cmask[bc * 128 + t];
  else qnv[t - 128] = qnrm[bq * 128 + (t - 128)];
  {
    constexpr int GU4 = LS / 8;
    const uint4* gsrc = (const uint4*)(Gbf + (size_t)bc * GC * LS * LS);
    for (int idx = t; idx < 128 * GU4; idx += 256) {
      int row = idx / GU4, u = idx % GU4;
      *(uint4*)(sm + GOFF + row * GST + u * 16) = gsrc[idx];
    }
  }

  // ---- Phase 1: 128x128x512 score GEMM, 4x4 16-tiles per wave ----
  const int sT0 = (w & 1) * 4, nT0 = (w >> 1) * 4;
  f32x4 acc[4][4];
#pragma unroll
  for (int si = 0; si < 4; si++)
#pragma unroll
    for (int ni = 0; ni < 4; ni++) acc[si][ni] = {0.f, 0.f, 0.f, 0.f};

  uint4 pf[8];
  auto gload = [&](int ch) {
#pragma unroll
    for (int i = 0; i < 8; i++) {
      int idx = t + i * 256;
      int row = idx >> 3, u = idx & 7;
      const unsigned short* src =
          (row < 128) ? (aBase + ((size_t)row << 9)) : (bBase + ((size_t)(row - 128) << 9));
      pf[i] = *(const uint4*)(src + ch * 64 + u * 8);
    }
  };
  gload(0);
  for (int ch = 0; ch < 8; ch++) {
    __syncthreads();  // prior MFMA reads done
#pragma unroll
    for (int i = 0; i < 8; i++) {
      int idx = t + i * 256;
      int row = idx >> 3, u = idx & 7;
      *(uint4*)(sm + row * SROW + u * 16) = pf[i];
    }
    __syncthreads();  // staging ready
    if (ch < 7) gload(ch + 1);  // prefetch overlaps MFMA
#pragma unroll
    for (int kk = 0; kk < 2; kk++) {
      short8 av[4], bv[4];
#pragma unroll
      for (int si = 0; si < 4; si++)
        av[si] = *(const short8*)(sm + ((sT0 + si) * 16 + m16) * SROW + kk * 64 + grp * 16);
#pragma unroll
      for (int ni = 0; ni < 4; ni++)
        bv[ni] = *(const short8*)(sm + BOFF + ((nT0 + ni) * 16 + m16) * SROW + kk * 64 + grp * 16);
#pragma unroll
      for (int si = 0; si < 4; si++)
#pragma unroll
        for (int ni = 0; ni < 4; ni++)
          acc[si][ni] = __builtin_amdgcn_mfma_f32_16x16x32_bf16(av[si], bv[ni], acc[si][ni], 0, 0, 0);
    }
  }
  __syncthreads();
  // write S0 bf16 [n][m]; C-layout rows (grp*4+r) are consecutive m -> 8B store
#pragma unroll
  for (int si = 0; si < 4; si++)
#pragma unroll
    for (int ni = 0; ni < 4; ni++) {
      int n = (nT0 + ni) * 16 + m16;
      int m0 = (sT0 + si) * 16 + grp * 4;
      ushort4 p;
      p.x = f2bf(acc[si][ni][0]); p.y = f2bf(acc[si][ni][1]);
      p.z = f2bf(acc[si][ni][2]); p.w = f2bf(acc[si][ni][3]);
      *(ushort4*)(sm + soff(n) + m0 * 2) = p;
    }
  __syncthreads();

  // ---- Phase 2a: rinv[(q),m] = 1/(||lrelu(S0[m, q-cols])|| + eps) ----
  {
    const int m = t & 127;
    for (int qi = t >> 7; qi < GQ; qi += 2) {
      float ss = 0.f;
#pragma unroll 8
      for (int l = 0; l < LQ; l++) {
        int n = qi * LQ + l;
        float v = bf2f(*(const unsigned short*)(sm + soff(n) + m * 2));
        v = v > 0.f ? v : 0.1f * v;
        ss = fmaf(v, v, ss);
      }
      rinvv[qi * 128 + m] = 1.0f / (sqrtf(ss) + EPSF);
    }
  }
  __syncthreads();

  // ---- Phase 2b: per-(n,c) softmax in place; w12 ----
  {
    const int n = t & 127;
    const int qi = n / LQ;
    for (int ci = t >> 7; ci < GC; ci += 2) {
      char* rowp = sm + soff(n) + ci * LS * 2;
      uint2 pk[LS / 4];
#pragma unroll
      for (int u = 0; u < LS / 4; u++) pk[u] = *(const uint2*)(rowp + u * 8);
      const float* rv = rinvv + qi * 128 + ci * LS;
      const float* cv = cmv + ci * LS;
      float mx = -1e30f;
#pragma unroll
      for (int u = 0; u < LS / 4; u++) {
        float v0 = __uint_as_float(pk[u].x << 16);
        float v1 = __uint_as_float(pk[u].x & 0xffff0000u);
        float v2 = __uint_as_float(pk[u].y << 16);
        float v3 = __uint_as_float(pk[u].y & 0xffff0000u);
        int s = u * 4;
        float g0 = LAM * fmaf(v0 > 0.f ? v0 : 0.1f * v0, rv[s], cv[s]);
        float g1 = LAM * fmaf(v1 > 0.f ? v1 : 0.1f * v1, rv[s + 1], cv[s + 1]);
        float g2 = LAM * fmaf(v2 > 0.f ? v2 : 0.1f * v2, rv[s + 2], cv[s + 2]);
        float g3 = LAM * fmaf(v3 > 0.f ? v3 : 0.1f * v3, rv[s + 3], cv[s + 3]);
        mx = fmaxf(mx, fmaxf(fmaxf(g0, g1), fmaxf(g2, g3)));
      }
      float sum = 0.f;
#pragma unroll
      for (int u = 0; u < LS / 4; u++) {
        float v0 = __uint_as_float(pk[u].x << 16);
        float v1 = __uint_as_float(pk[u].x & 0xffff0000u);
        float v2 = __uint_as_float(pk[u].y << 16);
        float v3 = __uint_as_float(pk[u].y & 0xffff0000u);
        int s = u * 4;
        sum += __expf(LAM * fmaf(v0 > 0.f ? v0 : 0.1f * v0, rv[s], cv[s]) - mx);
        sum += __expf(LAM * fmaf(v1 > 0.f ? v1 : 0.1f * v1, rv[s + 1], cv[s + 1]) - mx);
        sum += __expf(LAM * fmaf(v2 > 0.f ? v2 : 0.1f * v2, rv[s + 2], cv[s + 2]) - mx);
        sum += __expf(LAM * fmaf(v3 > 0.f ? v3 : 0.1f * v3, rv[s + 3], cv[s + 3]) - mx);
      }
      float inv = 1.0f / sum;
      float w12 = 0.f;
#pragma unroll
      for (int u = 0; u < LS / 4; u++) {
        float v0 = __uint_as_float(pk[u].x << 16);
        float v1 = __uint_as_float(pk[u].x & 0xffff0000u);
        float v2 = __uint_as_float(pk[u].y << 16);
        float v3 = __uint_as_float(pk[u].y & 0xffff0000u);
        int s = u * 4;
        float a0 = __expf(LAM * fmaf(v0 > 0.f ? v0 : 0.1f * v0, rv[s], cv[s]) - mx) * inv;
        float a1 = __expf(LAM * fmaf(v1 > 0.f ? v1 : 0.1f * v1, rv[s + 1], cv[s + 1]) - mx) * inv;
        float a2 = __expf(LAM * fmaf(v2 > 0.f ? v2 : 0.1f * v2, rv[s + 2], cv[s + 2]) - mx) * inv;
        float a3 = __expf(LAM * fmaf(v3 > 0.f ? v3 : 0.1f * v3, rv[s + 3], cv[s + 3]) - mx) * inv;
        w12 = fmaf(a0, v0, w12); w12 = fmaf(a1, v1, w12);
        w12 = fmaf(a2, v2, w12); w12 = fmaf(a3, v3, w12);
        uint2 o;
        o.x = (unsigned)f2bf(a0) | ((unsigned)f2bf(a1) << 16);
        o.y = (unsigned)f2bf(a2) | ((unsigned)f2bf(a3) << 16);
        *(uint2*)(rowp + u * 8) = o;
      }
      w12v[ci * 128 + n] = w12;
    }
  }
  __syncthreads();

  // ---- Phase 3: per-c U = G_c @ attn_c (MFMA); wn2 from C-regs ----
  {
    constexpr int WPC = 4 / GC;   // waves per context
    constexpr int KS3 = LS / 32;  // 2 (i2t) / 1 (t2i)
    const int c3 = w / WPC, hf = w % WPC;
    f32x4 u[2][8];
#pragma unroll
    for (int mi = 0; mi < 2; mi++)
#pragma unroll
      for (int nt = 0; nt < 8; nt++) u[mi][nt] = {0.f, 0.f, 0.f, 0.f};
#pragma unroll
    for (int ks = 0; ks < KS3; ks++) {
      short8 a2[2], b2[8];
#pragma unroll
      for (int mi = 0; mi < 2; mi++) {
        int sp = (hf * 2 + mi) * 16 + m16;
        a2[mi] = *(const short8*)(sm + GOFF + (c3 * LS + sp) * GST + ks * 64 + grp * 16);
      }
#pragma unroll
      for (int nt = 0; nt < 8; nt++) {
        const char* p = sm + soff(nt * 16 + m16) + c3 * LS * 2 + ks * 64 + grp * 16;
        union { uint2 h[2]; short8 v; } bb;
        bb.h[0] = *(const uint2*)(p);
        bb.h[1] = *(const uint2*)(p + 8);
        b2[nt] = bb.v;
      }
#pragma unroll
      for (int mi = 0; mi < 2; mi++)
#pragma unroll
        for (int nt = 0; nt < 8; nt++)
          u[mi][nt] = __builtin_amdgcn_mfma_f32_16x16x32_bf16(a2[mi], b2[nt], u[mi][nt], 0, 0, 0);
    }
    float wp[8];
#pragma unroll
    for (int nt = 0; nt < 8; nt++) wp[nt] = 0.f;
#pragma unroll
    for (int nt = 0; nt < 8; nt++) {
#pragma unroll
      for (int mi = 0; mi < 2; mi++) {
        int sp = (hf * 2 + mi) * 16 + grp * 4;
        const unsigned short* ap =
            (const unsigned short*)(sm + soff(nt * 16 + m16) + (c3 * LS + sp) * 2);
        wp[nt] += bf2f(ap[0]) * u[mi][nt][0] + bf2f(ap[1]) * u[mi][nt][1] +
                  bf2f(ap[2]) * u[mi][nt][2] + bf2f(ap[3]) * u[mi][nt][3];
      }
    }
#pragma unroll
    for (int o = 16; o < 64; o <<= 1)
#pragma unroll
      for (int nt = 0; nt < 8; nt++) wp[nt] += __shfl_xor(wp[nt], o);
    if (lane < 16) {
#pragma unroll
      for (int nt = 0; nt < 8; nt++) psum[w * 128 + nt * 16 + lane] = wp[nt];
    }
  }
  __syncthreads();

  // ---- Final: cos + mean over l -> sim ----
  {
    constexpr int WPC = 4 / GC;
    const int p = t >> 5, l0 = t & 31;
    const int cc = p / GQ, qi = p % GQ;
    float sum = 0.f;
#pragma unroll
    for (int li = 0; li < LQ / 32; li++) {
      int n = qi * LQ + l0 + li * 32;
      float nq = qnv[n];
      float wn2 = 0.f;
#pragma unroll
      for (int h = 0; h < WPC; h++) wn2 += psum[(cc * WPC + h) * 128 + n];
      float w12 = w12v[cc * 128 + n];
      float denom = fmaxf(nq * sqrtf(fmaxf(wn2, 0.f)), 1e-8f);
      sum += (nq + EPSF) * w12 / denom;
    }
#pragma unroll
    for (int o = 1; o < 32; o <<= 1) sum += __shfl_xor(sum, o);
    if (l0 == 0) sim[(bc * GC + cc) * 128 + bq * GQ + qi] = sum * (1.0f / (float)LQ);
  }
}

// ---------------------------------------------------------------------------
// Loss reductions (unchanged, exact).
// ---------------------------------------------------------------------------
__global__ __launch_bounds__(128) void loss_rows(
    const float* __restrict__ gsim, const float* __restrict__ i2t,
    const float* __restrict__ t2i, float* __restrict__ grow,
    float* __restrict__ gcol, float* __restrict__ lrow) {
  const int i = blockIdx.x, j = threadIdx.x;
  const int B = 128;
  __shared__ float sh[2];
  auto bmax = [&](float v) -> float {
#pragma unroll
    for (int o = 32; o; o >>= 1) v = fmaxf(v, __shfl_down(v, o));
    if ((j & 63) == 0) sh[j >> 6] = v;
    __syncthreads();
    float r = fmaxf(sh[0], sh[1]);
    __syncthreads();
    return r;
  };
  auto bsum = [&](float v) -> float {
#pragma unroll
    for (int o = 32; o; o >>= 1) v += __shfl_down(v, o);
    if ((j & 63) == 0) sh[j >> 6] = v;
    __syncthreads();
    float r = sh[0] + sh[1];
    __syncthreads();
    return r;
  };
  float xr = gsim[i * B + j] * 20.f;
  float xc = gsim[j * B + i] * 20.f;
  float sc = (i2t[i * B + j] + t2i[j * B + i]) * LAM;
  float mr = bmax(xr);
  float lser = mr + logf(bsum(__expf(xr - mr)));
  float mc = bmax(xc);
  float lsec = mc + logf(bsum(__expf(xc - mc)));
  float ml = bmax(sc);
  float lsel = ml + logf(bsum(__expf(sc - ml)));
  float pred = __expf(sc - lsel);
  float logLab = (i == j) ? logf(1.0f + 1e-6f) : logf(1e-6f);
  float tsum = bsum(pred * (sc - lsel - logLab));
  if (j == 0) {
    float d = gsim[i * B + i] * 20.f;
    grow[i] = d - lser;
    gcol[i] = d - lsec;
    lrow[i] = tsum;
  }
}

__global__ __launch_bounds__(128) void loss_final(const float* __restrict__ grow,
                                                  const float* __restrict__ gcol,
                                                  const float* __restrict__ lrow,
                                                  float* __restrict__ out) {
  const int j = threadIdx.x;
  __shared__ float sh[2];
  auto bsum = [&](float v) -> float {
#pragma unroll
    for (int o = 32; o; o >>= 1) v += __shfl_down(v, o);
    if ((j & 63) == 0) sh[j >> 6] = v;
    __syncthreads();
    float r = sh[0] + sh[1];
    __syncthreads();
    return r;
  };
  float a = bsum(grow[j]);
  float b = bsum(gcol[j]);
  float c = bsum(lrow[j]);
  if (j == 0) {
    float gl = -(a / 128.f) - (b / 128.f);
    float ll = c / 128.f;
    out[0] = gl + ll;
    out[1] = gl;
    out[2] = ll;
  }
}

extern "C" void kernel_launch(void* const* d_in, const int* in_sizes, int n_in,
                              void* d_out, int out_size, void* d_ws,
                              size_t ws_size, hipStream_t stream) {
  const float* gsim = (const float*)d_in[0];  // (128,128)
  const float* im = (const float*)d_in[1];    // (128,64,512)
  const float* s = (const float*)d_in[2];     // (128,32,512)
  const float* im_m = (const float*)d_in[3];  // (128,64)
  const float* s_m = (const float*)d_in[5];   // (128,32)
  float* out = (float*)d_out;

  float* ws = (float*)d_ws;
  float* nim = ws;                                         // 8192
  float* ns = ws + 8192;                                   // 4096
  float* i2t = ws + 12288;                                 // 16384
  float* t2i = ws + 28672;                                 // 16384
  float* grow = ws + 45056;                                // 128
  float* gcol = ws + 45184;                                // 128
  float* lrow = ws + 45312;                                // 128
  unsigned short* Gim = (unsigned short*)(ws + 45440);     // 128*64*64 bf16
  unsigned short* Gs = (unsigned short*)(ws + 307584);     // 128*32*32 bf16
  unsigned short* imn = (unsigned short*)(ws + 373120);    // 128*64*512 bf16
  unsigned short* sn = (unsigned short*)(ws + 2470272);    // 128*32*512 bf16

  norm_convert<<<dim3(3072), dim3(256), 0, stream>>>(im, s, nim, ns, imn, sn);
  gram_mfma<64><<<dim3(128), dim3(256), 0, stream>>>(imn, Gim);
  gram_mfma<32><<<dim3(128), dim3(256), 0, stream>>>(sn, Gs);
  // i2t: ctx=images(LS=64,GC=2), qry=captions(LQ=32,GQ=4)
  attn_tile<64, 32, 2, 4><<<dim3(32, 64), dim3(256), 0, stream>>>(
      imn, sn, Gim, ns, im_m, i2t);
  // t2i: ctx=captions(LS=32,GC=4), qry=images(LQ=64,GQ=2)
  attn_tile<32, 64, 4, 2><<<dim3(64, 32), dim3(256), 0, stream>>>(
      sn, imn, Gs, nim, s_m, t2i);
  loss_rows<<<dim3(128), dim3(128), 0, stream>>>(gsim, i2t, t2i, grow, gcol, lrow);
  loss_final<<<dim3(1), dim3(128), 0, stream>>>(grow, gcol, lrow, out);
}

// Round 6
// 243.058 us; speedup vs baseline: 1.6673x; 1.6673x over previous
//
#include <hip/hip_runtime.h>
#include <math.h>

#define EPSF 1e-8f
#define LAM 20.0f

typedef short short8 __attribute__((ext_vector_type(8)));
typedef float f32x4 __attribute__((ext_vector_type(4)));

__device__ __forceinline__ unsigned short f2bf(float x) {
  unsigned u = __float_as_uint(x);
  u += 0x7fffu + ((u >> 16) & 1u);
  return (unsigned short)(u >> 16);
}
__device__ __forceinline__ float bf2f(unsigned short h) {
  return __uint_as_float(((unsigned)h) << 16);
}

// ---------------------------------------------------------------------------
// Kernel 1: row norms + bf16 normalized copies.
// ---------------------------------------------------------------------------
__global__ __launch_bounds__(256) void norm_convert(
    const float* __restrict__ im, const float* __restrict__ s,
    float* __restrict__ nim, float* __restrict__ ns,
    unsigned short* __restrict__ imn, unsigned short* __restrict__ sn) {
  int row = blockIdx.x * 4 + (threadIdx.x >> 6);
  int lane = threadIdx.x & 63;
  const float* src;
  unsigned short* dst;
  float* ndst;
  if (row < 8192) {
    src = im + ((size_t)row << 9);
    dst = imn + ((size_t)row << 9);
    ndst = nim + row;
  } else {
    int r = row - 8192;
    src = s + ((size_t)r << 9);
    dst = sn + ((size_t)r << 9);
    ndst = ns + r;
  }
  float4 v0 = ((const float4*)src)[lane * 2];
  float4 v1 = ((const float4*)src)[lane * 2 + 1];
  float ss = 0.f;
  ss = fmaf(v0.x, v0.x, ss); ss = fmaf(v0.y, v0.y, ss);
  ss = fmaf(v0.z, v0.z, ss); ss = fmaf(v0.w, v0.w, ss);
  ss = fmaf(v1.x, v1.x, ss); ss = fmaf(v1.y, v1.y, ss);
  ss = fmaf(v1.z, v1.z, ss); ss = fmaf(v1.w, v1.w, ss);
#pragma unroll
  for (int o = 32; o; o >>= 1) ss += __shfl_xor(ss, o);
  float n = sqrtf(ss);
  if (lane == 0) *ndst = n;
  float ci = 1.0f / (n + EPSF);
  union { unsigned short us[8]; uint4 v; } p;
  p.us[0] = f2bf(v0.x * ci); p.us[1] = f2bf(v0.y * ci);
  p.us[2] = f2bf(v0.z * ci); p.us[3] = f2bf(v0.w * ci);
  p.us[4] = f2bf(v1.x * ci); p.us[5] = f2bf(v1.y * ci);
  p.us[6] = f2bf(v1.z * ci); p.us[7] = f2bf(v1.w * ci);
  ((uint4*)dst)[lane] = p.v;
}

// ---------------------------------------------------------------------------
// Kernel 2: bf16 Gram matrices via MFMA. One block per c. G = ctxn @ ctxn^T.
// ---------------------------------------------------------------------------
template <int LS>
__global__ __launch_bounds__(256, 2) void gram_mfma(
    const unsigned short* __restrict__ ctxn, unsigned short* __restrict__ Gbf) {
  constexpr int RW = (LS / 16) / 2;
  __shared__ __align__(16) char sm[LS * 272];
  const int c = blockIdx.x, t = threadIdx.x;
  const int w = t >> 6, lane = t & 63, m16 = lane & 15, grp = lane >> 4;
  const int rT0 = (w & 1) * RW, cT0 = (w >> 1) * RW;
  const unsigned short* base = ctxn + ((size_t)c * LS << 9);
  f32x4 g[RW][RW];
#pragma unroll
  for (int ri = 0; ri < RW; ri++)
#pragma unroll
    for (int ci = 0; ci < RW; ci++) g[ri][ci] = {0.f, 0.f, 0.f, 0.f};

  for (int ch = 0; ch < 4; ch++) {
    __syncthreads();
    for (int idx = t; idx < LS * 16; idx += 256) {
      int row = idx >> 4, u = idx & 15;
      *(uint4*)(sm + row * 272 + u * 16) =
          ((const uint4*)(base + ((size_t)row << 9) + (ch << 7)))[u];
    }
    __syncthreads();
#pragma unroll
    for (int kk = 0; kk < 4; kk++) {
      short8 a[RW], b[RW];
#pragma unroll
      for (int ri = 0; ri < RW; ri++)
        a[ri] = *(const short8*)(sm + ((rT0 + ri) * 16 + m16) * 272 + kk * 64 + grp * 16);
#pragma unroll
      for (int ci = 0; ci < RW; ci++)
        b[ci] = *(const short8*)(sm + ((cT0 + ci) * 16 + m16) * 272 + kk * 64 + grp * 16);
#pragma unroll
      for (int ri = 0; ri < RW; ri++)
#pragma unroll
        for (int ci = 0; ci < RW; ci++)
          g[ri][ci] = __builtin_amdgcn_mfma_f32_16x16x32_bf16(a[ri], b[ci], g[ri][ci], 0, 0, 0);
    }
  }
#pragma unroll
  for (int ri = 0; ri < RW; ri++)
#pragma unroll
    for (int ci = 0; ci < RW; ci++)
#pragma unroll
      for (int r = 0; r < 4; r++) {
        int s = (rT0 + ri) * 16 + grp * 4 + r;
        int sp = (cT0 + ci) * 16 + m16;
        Gbf[(size_t)c * LS * LS + s * LS + sp] = f2bf(g[ri][ci][r]);
      }
}

// ---------------------------------------------------------------------------
// Kernel 3: macro-tiled fused attention (R5 structure, de-pressured).
// Block = 128x128 tile spanning GC contexts x GQ queries.
//   - direct load->LDS staging (no register prefetch array)
//   - softmax re-reads LDS per pass (no pk[] cache)
//   - single shared f32x4 regs[16] accumulator for P1 and P3
// ---------------------------------------------------------------------------
template <int LS, int LQ, int GC, int GQ>
__global__ __launch_bounds__(256, 2) void attn_tile(
    const unsigned short* __restrict__ ctxn,  // (128,LS,512) bf16
    const unsigned short* __restrict__ qryn,  // (128,LQ,512) bf16
    const unsigned short* __restrict__ Gbf,   // (128,LS,LS) bf16
    const float* __restrict__ qnrm,           // 128*LQ raw query norms
    const float* __restrict__ cmask,          // (128,LS)
    float* __restrict__ sim) {
  static_assert(GC * LS == 128 && GQ * LQ == 128, "tile must be 128x128");
  constexpr int SROW = 144;                 // staging row stride (64 bf16 + pad)
  constexpr int S0P = 264;                  // S0/attn row pitch (bytes)
  constexpr int GOFF = 256 * SROW;          // 36864: G region
  constexpr int GST = LS * 2 + 16;          // G row stride bytes
  constexpr int FOFF = GOFF + 128 * GST;    // float scratch
  constexpr int NF = GQ * 128 + GC * 128 + 512 + 256;
  static_assert(127 * S0P + 256 <= 256 * SROW, "S0 overflows staging alias");
  __shared__ __align__(16) char sm[FOFF + NF * 4];
  float* rinvv = (float*)(sm + FOFF);       // [GQ][128]
  float* w12v = rinvv + GQ * 128;           // [GC][128]
  float* psum = w12v + GC * 128;            // [4][128] wn2 wave partials
  float* cmv = psum + 512;                  // [128]
  float* qnv = cmv + 128;                   // [128]

  const int bq = blockIdx.x, bc = blockIdx.y, t = threadIdx.x;
  const int w = t >> 6, lane = t & 63, m16 = lane & 15, grp = lane >> 4;

  auto soff = [](int n) { return n * S0P; };

  const unsigned short* aBase = ctxn + ((size_t)bc << 16);  // bc*128*512
  const unsigned short* bBase = qryn + ((size_t)bq << 16);

  // ---- preload G, cmask, qnorms (ordering covered by P1 barriers) ----
  if (t < 128) cmv[t] = cmask[bc * 128 + t];
  else qnv[t - 128] = qnrm[bq * 128 + (t - 128)];
  {
    constexpr int GU4 = LS / 8;
    const uint4* gsrc = (const uint4*)(Gbf + (size_t)bc * GC * LS * LS);
    for (int idx = t; idx < 128 * GU4; idx += 256) {
      int row = idx / GU4, u = idx % GU4;
      *(uint4*)(sm + GOFF + row * GST + u * 16) = gsrc[idx];
    }
  }

  // shared accumulator file: P1 uses regs[si*4+ni], P3 uses regs[mi*8+nt]
  f32x4 regs[16];
#pragma unroll
  for (int i = 0; i < 16; i++) regs[i] = {0.f, 0.f, 0.f, 0.f};

  // ---- Phase 1: 128x128x512 score GEMM, 4x4 16-tiles per wave ----
  const int sT0 = (w & 1) * 4, nT0 = (w >> 1) * 4;
  for (int ch = 0; ch < 8; ch++) {
    __syncthreads();  // prior MFMA reads done
#pragma unroll
    for (int i = 0; i < 8; i++) {
      int idx = t + i * 256;
      int row = idx >> 3, u = idx & 7;
      const unsigned short* src =
          (row < 128) ? (aBase + ((size_t)row << 9)) : (bBase + ((size_t)(row - 128) << 9));
      *(uint4*)(sm + row * SROW + u * 16) = *(const uint4*)(src + ch * 64 + u * 8);
    }
    __syncthreads();  // staging ready
#pragma unroll
    for (int kk = 0; kk < 2; kk++) {
      short8 av[4], bv[4];
#pragma unroll
      for (int si = 0; si < 4; si++)
        av[si] = *(const short8*)(sm + ((sT0 + si) * 16 + m16) * SROW + kk * 64 + grp * 16);
#pragma unroll
      for (int ni = 0; ni < 4; ni++)
        bv[ni] = *(const short8*)(sm + (128 + (nT0 + ni) * 16 + m16) * SROW + kk * 64 + grp * 16);
#pragma unroll
      for (int si = 0; si < 4; si++)
#pragma unroll
        for (int ni = 0; ni < 4; ni++)
          regs[si * 4 + ni] = __builtin_amdgcn_mfma_f32_16x16x32_bf16(
              av[si], bv[ni], regs[si * 4 + ni], 0, 0, 0);
    }
  }
  __syncthreads();
  // write S0 bf16 [n][m]; C-layout rows (grp*4+r) are consecutive m -> 8B store
#pragma unroll
  for (int si = 0; si < 4; si++)
#pragma unroll
    for (int ni = 0; ni < 4; ni++) {
      int n = (nT0 + ni) * 16 + m16;
      int m0 = (sT0 + si) * 16 + grp * 4;
      f32x4 a = regs[si * 4 + ni];
      ushort4 p;
      p.x = f2bf(a[0]); p.y = f2bf(a[1]);
      p.z = f2bf(a[2]); p.w = f2bf(a[3]);
      *(ushort4*)(sm + soff(n) + m0 * 2) = p;
    }
  __syncthreads();

  // ---- Phase 2a: rinv[(q),m] = 1/(||lrelu(S0[m, q-cols])|| + eps) ----
  {
    const int m = t & 127;
    for (int qi = t >> 7; qi < GQ; qi += 2) {
      float ss = 0.f;
#pragma unroll 8
      for (int l = 0; l < LQ; l++) {
        int n = qi * LQ + l;
        float v = bf2f(*(const unsigned short*)(sm + soff(n) + m * 2));
        v = v > 0.f ? v : 0.1f * v;
        ss = fmaf(v, v, ss);
      }
      rinvv[qi * 128 + m] = 1.0f / (sqrtf(ss) + EPSF);
    }
  }
  __syncthreads();

  // ---- Phase 2b: per-(n,c) softmax in place; w12 (3 LDS passes, no cache) ---
  {
    const int n = t & 127;
    const int qi = n / LQ;
    for (int ci = t >> 7; ci < GC; ci += 2) {
      char* rowp = sm + soff(n) + ci * LS * 2;
      const float* rv = rinvv + qi * 128 + ci * LS;
      const float* cv = cmv + ci * LS;
      float mx = -1e30f;
#pragma unroll
      for (int u = 0; u < LS / 4; u++) {
        uint2 pk = *(const uint2*)(rowp + u * 8);
        float v0 = __uint_as_float(pk.x << 16);
        float v1 = __uint_as_float(pk.x & 0xffff0000u);
        float v2 = __uint_as_float(pk.y << 16);
        float v3 = __uint_as_float(pk.y & 0xffff0000u);
        int s = u * 4;
        float g0 = LAM * fmaf(v0 > 0.f ? v0 : 0.1f * v0, rv[s], cv[s]);
        float g1 = LAM * fmaf(v1 > 0.f ? v1 : 0.1f * v1, rv[s + 1], cv[s + 1]);
        float g2 = LAM * fmaf(v2 > 0.f ? v2 : 0.1f * v2, rv[s + 2], cv[s + 2]);
        float g3 = LAM * fmaf(v3 > 0.f ? v3 : 0.1f * v3, rv[s + 3], cv[s + 3]);
        mx = fmaxf(mx, fmaxf(fmaxf(g0, g1), fmaxf(g2, g3)));
      }
      float sum = 0.f;
#pragma unroll
      for (int u = 0; u < LS / 4; u++) {
        uint2 pk = *(const uint2*)(rowp + u * 8);
        float v0 = __uint_as_float(pk.x << 16);
        float v1 = __uint_as_float(pk.x & 0xffff0000u);
        float v2 = __uint_as_float(pk.y << 16);
        float v3 = __uint_as_float(pk.y & 0xffff0000u);
        int s = u * 4;
        sum += __expf(LAM * fmaf(v0 > 0.f ? v0 : 0.1f * v0, rv[s], cv[s]) - mx);
        sum += __expf(LAM * fmaf(v1 > 0.f ? v1 : 0.1f * v1, rv[s + 1], cv[s + 1]) - mx);
        sum += __expf(LAM * fmaf(v2 > 0.f ? v2 : 0.1f * v2, rv[s + 2], cv[s + 2]) - mx);
        sum += __expf(LAM * fmaf(v3 > 0.f ? v3 : 0.1f * v3, rv[s + 3], cv[s + 3]) - mx);
      }
      float inv = 1.0f / sum;
      float w12 = 0.f;
#pragma unroll
      for (int u = 0; u < LS / 4; u++) {
        uint2 pk = *(const uint2*)(rowp + u * 8);
        float v0 = __uint_as_float(pk.x << 16);
        float v1 = __uint_as_float(pk.x & 0xffff0000u);
        float v2 = __uint_as_float(pk.y << 16);
        float v3 = __uint_as_float(pk.y & 0xffff0000u);
        int s = u * 4;
        float a0 = __expf(LAM * fmaf(v0 > 0.f ? v0 : 0.1f * v0, rv[s], cv[s]) - mx) * inv;
        float a1 = __expf(LAM * fmaf(v1 > 0.f ? v1 : 0.1f * v1, rv[s + 1], cv[s + 1]) - mx) * inv;
        float a2 = __expf(LAM * fmaf(v2 > 0.f ? v2 : 0.1f * v2, rv[s + 2], cv[s + 2]) - mx) * inv;
        float a3 = __expf(LAM * fmaf(v3 > 0.f ? v3 : 0.1f * v3, rv[s + 3], cv[s + 3]) - mx) * inv;
        w12 = fmaf(a0, v0, w12); w12 = fmaf(a1, v1, w12);
        w12 = fmaf(a2, v2, w12); w12 = fmaf(a3, v3, w12);
        uint2 o;
        o.x = (unsigned)f2bf(a0) | ((unsigned)f2bf(a1) << 16);
        o.y = (unsigned)f2bf(a2) | ((unsigned)f2bf(a3) << 16);
        *(uint2*)(rowp + u * 8) = o;
      }
      w12v[ci * 128 + n] = w12;
    }
  }
  __syncthreads();

  // ---- Phase 3: per-c U = G_c @ attn_c (MFMA); wn2 from C-regs ----
  {
    constexpr int WPC = 4 / GC;   // waves per context
    constexpr int KS3 = LS / 32;  // 2 (i2t) / 1 (t2i)
    const int c3 = w / WPC, hf = w % WPC;
#pragma unroll
    for (int i = 0; i < 16; i++) regs[i] = {0.f, 0.f, 0.f, 0.f};
#pragma unroll
    for (int ks = 0; ks < KS3; ks++) {
      short8 a2[2], b2[8];
#pragma unroll
      for (int mi = 0; mi < 2; mi++) {
        int sp = (hf * 2 + mi) * 16 + m16;
        a2[mi] = *(const short8*)(sm + GOFF + (c3 * LS + sp) * GST + ks * 64 + grp * 16);
      }
#pragma unroll
      for (int nt = 0; nt < 8; nt++) {
        const char* p = sm + soff(nt * 16 + m16) + c3 * LS * 2 + ks * 64 + grp * 16;
        union { uint2 h[2]; short8 v; } bb;
        bb.h[0] = *(const uint2*)(p);
        bb.h[1] = *(const uint2*)(p + 8);
        b2[nt] = bb.v;
      }
#pragma unroll
      for (int mi = 0; mi < 2; mi++)
#pragma unroll
        for (int nt = 0; nt < 8; nt++)
          regs[mi * 8 + nt] = __builtin_amdgcn_mfma_f32_16x16x32_bf16(
              a2[mi], b2[nt], regs[mi * 8 + nt], 0, 0, 0);
    }
    float wp[8];
#pragma unroll
    for (int nt = 0; nt < 8; nt++) wp[nt] = 0.f;
#pragma unroll
    for (int nt = 0; nt < 8; nt++) {
#pragma unroll
      for (int mi = 0; mi < 2; mi++) {
        int sp = (hf * 2 + mi) * 16 + grp * 4;
        const unsigned short* ap =
            (const unsigned short*)(sm + soff(nt * 16 + m16) + (c3 * LS + sp) * 2);
        f32x4 uu = regs[mi * 8 + nt];
        wp[nt] += bf2f(ap[0]) * uu[0] + bf2f(ap[1]) * uu[1] +
                  bf2f(ap[2]) * uu[2] + bf2f(ap[3]) * uu[3];
      }
    }
#pragma unroll
    for (int o = 16; o < 64; o <<= 1)
#pragma unroll
      for (int nt = 0; nt < 8; nt++) wp[nt] += __shfl_xor(wp[nt], o);
    if (lane < 16) {
#pragma unroll
      for (int nt = 0; nt < 8; nt++) psum[w * 128 + nt * 16 + lane] = wp[nt];
    }
  }
  __syncthreads();

  // ---- Final: cos + mean over l -> sim ----
  {
    constexpr int WPC = 4 / GC;
    const int p = t >> 5, l0 = t & 31;
    const int cc = p / GQ, qi = p % GQ;
    float sum = 0.f;
#pragma unroll
    for (int li = 0; li < LQ / 32; li++) {
      int n = qi * LQ + l0 + li * 32;
      float nq = qnv[n];
      float wn2 = 0.f;
#pragma unroll
      for (int h = 0; h < WPC; h++) wn2 += psum[(cc * WPC + h) * 128 + n];
      float w12 = w12v[cc * 128 + n];
      float denom = fmaxf(nq * sqrtf(fmaxf(wn2, 0.f)), 1e-8f);
      sum += (nq + EPSF) * w12 / denom;
    }
#pragma unroll
    for (int o = 1; o < 32; o <<= 1) sum += __shfl_xor(sum, o);
    if (l0 == 0) sim[(bc * GC + cc) * 128 + bq * GQ + qi] = sum * (1.0f / (float)LQ);
  }
}

// ---------------------------------------------------------------------------
// Loss reductions (unchanged, exact).
// ---------------------------------------------------------------------------
__global__ __launch_bounds__(128) void loss_rows(
    const float* __restrict__ gsim, const float* __restrict__ i2t,
    const float* __restrict__ t2i, float* __restrict__ grow,
    float* __restrict__ gcol, float* __restrict__ lrow) {
  const int i = blockIdx.x, j = threadIdx.x;
  const int B = 128;
  __shared__ float sh[2];
  auto bmax = [&](float v) -> float {
#pragma unroll
    for (int o = 32; o; o >>= 1) v = fmaxf(v, __shfl_down(v, o));
    if ((j & 63) == 0) sh[j >> 6] = v;
    __syncthreads();
    float r = fmaxf(sh[0], sh[1]);
    __syncthreads();
    return r;
  };
  auto bsum = [&](float v) -> float {
#pragma unroll
    for (int o = 32; o; o >>= 1) v += __shfl_down(v, o);
    if ((j & 63) == 0) sh[j >> 6] = v;
    __syncthreads();
    float r = sh[0] + sh[1];
    __syncthreads();
    return r;
  };
  float xr = gsim[i * B + j] * 20.f;
  float xc = gsim[j * B + i] * 20.f;
  float sc = (i2t[i * B + j] + t2i[j * B + i]) * LAM;
  float mr = bmax(xr);
  float lser = mr + logf(bsum(__expf(xr - mr)));
  float mc = bmax(xc);
  float lsec = mc + logf(bsum(__expf(xc - mc)));
  float ml = bmax(sc);
  float lsel = ml + logf(bsum(__expf(sc - ml)));
  float pred = __expf(sc - lsel);
  float logLab = (i == j) ? logf(1.0f + 1e-6f) : logf(1e-6f);
  float tsum = bsum(pred * (sc - lsel - logLab));
  if (j == 0) {
    float d = gsim[i * B + i] * 20.f;
    grow[i] = d - lser;
    gcol[i] = d - lsec;
    lrow[i] = tsum;
  }
}

__global__ __launch_bounds__(128) void loss_final(const float* __restrict__ grow,
                                                  const float* __restrict__ gcol,
                                                  const float* __restrict__ lrow,
                                                  float* __restrict__ out) {
  const int j = threadIdx.x;
  __shared__ float sh[2];
  auto bsum = [&](float v) -> float {
#pragma unroll
    for (int o = 32; o; o >>= 1) v += __shfl_down(v, o);
    if ((j & 63) == 0) sh[j >> 6] = v;
    __syncthreads();
    float r = sh[0] + sh[1];
    __syncthreads();
    return r;
  };
  float a = bsum(grow[j]);
  float b = bsum(gcol[j]);
  float c = bsum(lrow[j]);
  if (j == 0) {
    float gl = -(a / 128.f) - (b / 128.f);
    float ll = c / 128.f;
    out[0] = gl + ll;
    out[1] = gl;
    out[2] = ll;
  }
}

extern "C" void kernel_launch(void* const* d_in, const int* in_sizes, int n_in,
                              void* d_out, int out_size, void* d_ws,
                              size_t ws_size, hipStream_t stream) {
  const float* gsim = (const float*)d_in[0];  // (128,128)
  const float* im = (const float*)d_in[1];    // (128,64,512)
  const float* s = (const float*)d_in[2];     // (128,32,512)
  const float* im_m = (const float*)d_in[3];  // (128,64)
  const float* s_m = (const float*)d_in[5];   // (128,32)
  float* out = (float*)d_out;

  float* ws = (float*)d_ws;
  float* nim = ws;                                         // 8192
  float* ns = ws + 8192;                                   // 4096
  float* i2t = ws + 12288;                                 // 16384
  float* t2i = ws + 28672;                                 // 16384
  float* grow = ws + 45056;                                // 128
  float* gcol = ws + 45184;                                // 128
  float* lrow = ws + 45312;                                // 128
  unsigned short* Gim = (unsigned short*)(ws + 45440);     // 128*64*64 bf16
  unsigned short* Gs = (unsigned short*)(ws + 307584);     // 128*32*32 bf16
  unsigned short* imn = (unsigned short*)(ws + 373120);    // 128*64*512 bf16
  unsigned short* sn = (unsigned short*)(ws + 2470272);    // 128*32*512 bf16

  norm_convert<<<dim3(3072), dim3(256), 0, stream>>>(im, s, nim, ns, imn, sn);
  gram_mfma<64><<<dim3(128), dim3(256), 0, stream>>>(imn, Gim);
  gram_mfma<32><<<dim3(128), dim3(256), 0, stream>>>(sn, Gs);
  // i2t: ctx=images(LS=64,GC=2), qry=captions(LQ=32,GQ=4)
  attn_tile<64, 32, 2, 4><<<dim3(32, 64), dim3(256), 0, stream>>>(
      imn, sn, Gim, ns, im_m, i2t);
  // t2i: ctx=captions(LS=32,GC=4), qry=images(LQ=64,GQ=2)
  attn_tile<32, 64, 4, 2><<<dim3(64, 32), dim3(256), 0, stream>>>(
      sn, imn, Gs, nim, s_m, t2i);
  loss_rows<<<dim3(128), dim3(128), 0, stream>>>(gsim, i2t, t2i, grow, gcol, lrow);
  loss_final<<<dim3(1), dim3(128), 0, stream>>>(grow, gcol, lrow, out);
}

// Round 7
// 223.766 us; speedup vs baseline: 1.8110x; 1.0862x over previous
//
#include <hip/hip_runtime.h>
#include <math.h>

#define EPSF 1e-8f
#define LAM 20.0f

typedef short short8 __attribute__((ext_vector_type(8)));
typedef float f32x4 __attribute__((ext_vector_type(4)));

__device__ __forceinline__ unsigned short f2bf(float x) {
  unsigned u = __float_as_uint(x);
  u += 0x7fffu + ((u >> 16) & 1u);
  return (unsigned short)(u >> 16);
}
__device__ __forceinline__ float bf2f(unsigned short h) {
  return __uint_as_float(((unsigned)h) << 16);
}

// ---------------------------------------------------------------------------
// Kernel 1: row norms + bf16 normalized copies.
// ---------------------------------------------------------------------------
__global__ __launch_bounds__(256) void norm_convert(
    const float* __restrict__ im, const float* __restrict__ s,
    float* __restrict__ nim, float* __restrict__ ns,
    unsigned short* __restrict__ imn, unsigned short* __restrict__ sn) {
  int row = blockIdx.x * 4 + (threadIdx.x >> 6);
  int lane = threadIdx.x & 63;
  const float* src;
  unsigned short* dst;
  float* ndst;
  if (row < 8192) {
    src = im + ((size_t)row << 9);
    dst = imn + ((size_t)row << 9);
    ndst = nim + row;
  } else {
    int r = row - 8192;
    src = s + ((size_t)r << 9);
    dst = sn + ((size_t)r << 9);
    ndst = ns + r;
  }
  float4 v0 = ((const float4*)src)[lane * 2];
  float4 v1 = ((const float4*)src)[lane * 2 + 1];
  float ss = 0.f;
  ss = fmaf(v0.x, v0.x, ss); ss = fmaf(v0.y, v0.y, ss);
  ss = fmaf(v0.z, v0.z, ss); ss = fmaf(v0.w, v0.w, ss);
  ss = fmaf(v1.x, v1.x, ss); ss = fmaf(v1.y, v1.y, ss);
  ss = fmaf(v1.z, v1.z, ss); ss = fmaf(v1.w, v1.w, ss);
#pragma unroll
  for (int o = 32; o; o >>= 1) ss += __shfl_xor(ss, o);
  float n = sqrtf(ss);
  if (lane == 0) *ndst = n;
  float ci = 1.0f / (n + EPSF);
  union { unsigned short us[8]; uint4 v; } p;
  p.us[0] = f2bf(v0.x * ci); p.us[1] = f2bf(v0.y * ci);
  p.us[2] = f2bf(v0.z * ci); p.us[3] = f2bf(v0.w * ci);
  p.us[4] = f2bf(v1.x * ci); p.us[5] = f2bf(v1.y * ci);
  p.us[6] = f2bf(v1.z * ci); p.us[7] = f2bf(v1.w * ci);
  ((uint4*)dst)[lane] = p.v;
}

// ---------------------------------------------------------------------------
// Kernel 2: bf16 Gram matrices via MFMA. One block per c. G = ctxn @ ctxn^T.
// ---------------------------------------------------------------------------
template <int LS>
__global__ __launch_bounds__(256, 2) void gram_mfma(
    const unsigned short* __restrict__ ctxn, unsigned short* __restrict__ Gbf) {
  constexpr int RW = (LS / 16) / 2;
  __shared__ __align__(16) char sm[LS * 272];
  const int c = blockIdx.x, t = threadIdx.x;
  const int w = t >> 6, lane = t & 63, m16 = lane & 15, grp = lane >> 4;
  const int rT0 = (w & 1) * RW, cT0 = (w >> 1) * RW;
  const unsigned short* base = ctxn + ((size_t)c * LS << 9);
  f32x4 g[RW][RW];
#pragma unroll
  for (int ri = 0; ri < RW; ri++)
#pragma unroll
    for (int ci = 0; ci < RW; ci++) g[ri][ci] = {0.f, 0.f, 0.f, 0.f};

  for (int ch = 0; ch < 4; ch++) {
    __syncthreads();
    for (int idx = t; idx < LS * 16; idx += 256) {
      int row = idx >> 4, u = idx & 15;
      *(uint4*)(sm + row * 272 + u * 16) =
          ((const uint4*)(base + ((size_t)row << 9) + (ch << 7)))[u];
    }
    __syncthreads();
#pragma unroll
    for (int kk = 0; kk < 4; kk++) {
      short8 a[RW], b[RW];
#pragma unroll
      for (int ri = 0; ri < RW; ri++)
        a[ri] = *(const short8*)(sm + ((rT0 + ri) * 16 + m16) * 272 + kk * 64 + grp * 16);
#pragma unroll
      for (int ci = 0; ci < RW; ci++)
        b[ci] = *(const short8*)(sm + ((cT0 + ci) * 16 + m16) * 272 + kk * 64 + grp * 16);
#pragma unroll
      for (int ri = 0; ri < RW; ri++)
#pragma unroll
        for (int ci = 0; ci < RW; ci++)
          g[ri][ci] = __builtin_amdgcn_mfma_f32_16x16x32_bf16(a[ri], b[ci], g[ri][ci], 0, 0, 0);
    }
  }
#pragma unroll
  for (int ri = 0; ri < RW; ri++)
#pragma unroll
    for (int ci = 0; ci < RW; ci++)
#pragma unroll
      for (int r = 0; r < 4; r++) {
        int s = (rT0 + ri) * 16 + grp * 4 + r;
        int sp = (cT0 + ci) * 16 + m16;
        Gbf[(size_t)c * LS * LS + s * LS + sp] = f2bf(g[ri][ci][r]);
      }
}

// ---------------------------------------------------------------------------
// Kernel 3: macro-tiled fused attention (R6 structure, occupancy-tuned).
//   - G fragments preloaded into registers (no LDS G region) -> 3 blocks/CU
//   - one-pass softmax: analytic max bound LAM*(1+max(cmask)); stores
//     UNNORMALIZED e (bf16); inv folded into epilogue (exact softmax algebra)
//   - vectorized rinv pass (b64 reads)
// ---------------------------------------------------------------------------
template <int LS, int LQ, int GC, int GQ>
__global__ __launch_bounds__(256, 3) void attn_tile(
    const unsigned short* __restrict__ ctxn,  // (128,LS,512) bf16
    const unsigned short* __restrict__ qryn,  // (128,LQ,512) bf16
    const unsigned short* __restrict__ Gbf,   // (128,LS,LS) bf16
    const float* __restrict__ qnrm,           // 128*LQ raw query norms
    const float* __restrict__ cmask,          // (128,LS)
    float* __restrict__ sim) {
  static_assert(GC * LS == 128 && GQ * LQ == 128, "tile must be 128x128");
  constexpr int SROW = 144;                 // staging row stride (64 bf16 + pad)
  constexpr int S0P = 264;                  // S0/e row pitch (bytes)
  constexpr int FOFF = 256 * SROW;          // float scratch after staging
  constexpr int WPC = 4 / GC;               // waves per context in P3
  constexpr int KS3 = LS / 32;              // P3 k-steps: 2 (i2t) / 1 (t2i)
  static_assert(127 * S0P + 256 <= 256 * SROW, "S0 overflows staging alias");
  __shared__ __align__(16) char sm[FOFF + (GQ * 128 + 2 * GC * 128 + 512 + 256 + 8) * 4];
  float* rinvv = (float*)(sm + FOFF);       // [GQ][128]
  float* sumev = rinvv + GQ * 128;          // [GC][128]  sum e*v
  float* invv = sumev + GC * 128;           // [GC][128]  1/sum e
  float* psum = invv + GC * 128;            // [4][128] wn2 wave partials
  float* cmv = psum + 512;                  // [128]
  float* qnv = cmv + 128;                   // [128]
  float* cmmaxv = qnv + 128;                // [GC]

  const int bq = blockIdx.x, bc = blockIdx.y, t = threadIdx.x;
  const int w = t >> 6, lane = t & 63, m16 = lane & 15, grp = lane >> 4;

  auto soff = [](int n) { return n * S0P; };

  const unsigned short* aBase = ctxn + ((size_t)bc << 16);  // bc*128*512
  const unsigned short* bBase = qryn + ((size_t)bq << 16);

  // ---- preload cmask, qnorms; G fragments -> registers ----
  if (t < 128) cmv[t] = cmask[bc * 128 + t];
  else qnv[t - 128] = qnrm[bq * 128 + (t - 128)];
  const int c3 = w / WPC, hf = w % WPC;
  short8 g_a[2][KS3];
  {
    const unsigned short* gB = Gbf + (size_t)bc * GC * LS * LS + c3 * LS * LS;
#pragma unroll
    for (int mi = 0; mi < 2; mi++) {
      int sp = (hf * 2 + mi) * 16 + m16;
#pragma unroll
      for (int ks = 0; ks < KS3; ks++)
        g_a[mi][ks] = *(const short8*)(gB + sp * LS + ks * 32 + grp * 8);
    }
  }

  // shared accumulator file: P1 uses regs[si*4+ni], P3 uses regs[mi*8+nt]
  f32x4 regs[16];
#pragma unroll
  for (int i = 0; i < 16; i++) regs[i] = {0.f, 0.f, 0.f, 0.f};

  // ---- Phase 1: 128x128x512 score GEMM, 4x4 16-tiles per wave ----
  const int sT0 = (w & 1) * 4, nT0 = (w >> 1) * 4;
  for (int ch = 0; ch < 8; ch++) {
    __syncthreads();  // prior MFMA reads done
#pragma unroll
    for (int i = 0; i < 8; i++) {
      int idx = t + i * 256;
      int row = idx >> 3, u = idx & 7;
      const unsigned short* src =
          (row < 128) ? (aBase + ((size_t)row << 9)) : (bBase + ((size_t)(row - 128) << 9));
      *(uint4*)(sm + row * SROW + u * 16) = *(const uint4*)(src + ch * 64 + u * 8);
    }
    __syncthreads();  // staging ready
#pragma unroll
    for (int kk = 0; kk < 2; kk++) {
      short8 av[4], bv[4];
#pragma unroll
      for (int si = 0; si < 4; si++)
        av[si] = *(const short8*)(sm + ((sT0 + si) * 16 + m16) * SROW + kk * 64 + grp * 16);
#pragma unroll
      for (int ni = 0; ni < 4; ni++)
        bv[ni] = *(const short8*)(sm + (128 + (nT0 + ni) * 16 + m16) * SROW + kk * 64 + grp * 16);
#pragma unroll
      for (int si = 0; si < 4; si++)
#pragma unroll
        for (int ni = 0; ni < 4; ni++)
          regs[si * 4 + ni] = __builtin_amdgcn_mfma_f32_16x16x32_bf16(
              av[si], bv[ni], regs[si * 4 + ni], 0, 0, 0);
    }
  }
  __syncthreads();
  // write S0 bf16 [n][m]; C-layout rows (grp*4+r) are consecutive m -> 8B store
#pragma unroll
  for (int si = 0; si < 4; si++)
#pragma unroll
    for (int ni = 0; ni < 4; ni++) {
      int n = (nT0 + ni) * 16 + m16;
      int m0 = (sT0 + si) * 16 + grp * 4;
      f32x4 a = regs[si * 4 + ni];
      ushort4 p;
      p.x = f2bf(a[0]); p.y = f2bf(a[1]);
      p.z = f2bf(a[2]); p.w = f2bf(a[3]);
      *(ushort4*)(sm + soff(n) + m0 * 2) = p;
    }
  __syncthreads();

  // ---- Phase 2a: rinv (vectorized b64) + per-ci cmask max ----
  {
    if (t < GQ * 32) {
      int qi = t >> 5, mg = (t & 31) * 4;
      float s0 = 0.f, s1 = 0.f, s2 = 0.f, s3 = 0.f;
      for (int l = 0; l < LQ; l++) {
        uint2 pk = *(const uint2*)(sm + soff(qi * LQ + l) + mg * 2);
        float v0 = __uint_as_float(pk.x << 16);
        float v1 = __uint_as_float(pk.x & 0xffff0000u);
        float v2 = __uint_as_float(pk.y << 16);
        float v3 = __uint_as_float(pk.y & 0xffff0000u);
        v0 = v0 > 0.f ? v0 : 0.1f * v0;
        v1 = v1 > 0.f ? v1 : 0.1f * v1;
        v2 = v2 > 0.f ? v2 : 0.1f * v2;
        v3 = v3 > 0.f ? v3 : 0.1f * v3;
        s0 = fmaf(v0, v0, s0); s1 = fmaf(v1, v1, s1);
        s2 = fmaf(v2, v2, s2); s3 = fmaf(v3, v3, s3);
      }
      rinvv[qi * 128 + mg + 0] = 1.0f / (sqrtf(s0) + EPSF);
      rinvv[qi * 128 + mg + 1] = 1.0f / (sqrtf(s1) + EPSF);
      rinvv[qi * 128 + mg + 2] = 1.0f / (sqrtf(s2) + EPSF);
      rinvv[qi * 128 + mg + 3] = 1.0f / (sqrtf(s3) + EPSF);
    } else if (t < GQ * 32 + GC) {
      int ci = t - GQ * 32;
      float mx = cmv[ci * LS];
      for (int s = 1; s < LS; s++) mx = fmaxf(mx, cmv[ci * LS + s]);
      cmmaxv[ci] = mx;
    }
  }
  __syncthreads();

  // ---- Phase 2b: ONE-pass softmax (analytic max); store unnormalized e ----
  {
    const int n = t & 127;
    const int qi = n / LQ;
    for (int ci = t >> 7; ci < GC; ci += 2) {
      char* rowp = sm + soff(n) + ci * LS * 2;
      const float* rv = rinvv + qi * 128 + ci * LS;
      const float* cv = cmv + ci * LS;
      const float mxc = LAM * (1.0f + cmmaxv[ci]);
      float sum = 0.f, sev = 0.f;
#pragma unroll
      for (int u = 0; u < LS / 4; u++) {
        uint2 pk = *(const uint2*)(rowp + u * 8);
        float v0 = __uint_as_float(pk.x << 16);
        float v1 = __uint_as_float(pk.x & 0xffff0000u);
        float v2 = __uint_as_float(pk.y << 16);
        float v3 = __uint_as_float(pk.y & 0xffff0000u);
        int s = u * 4;
        float l0 = v0 > 0.f ? v0 : 0.1f * v0;
        float l1 = v1 > 0.f ? v1 : 0.1f * v1;
        float l2 = v2 > 0.f ? v2 : 0.1f * v2;
        float l3 = v3 > 0.f ? v3 : 0.1f * v3;
        float e0 = __expf(LAM * fmaf(l0, rv[s + 0], cv[s + 0]) - mxc);
        float e1 = __expf(LAM * fmaf(l1, rv[s + 1], cv[s + 1]) - mxc);
        float e2 = __expf(LAM * fmaf(l2, rv[s + 2], cv[s + 2]) - mxc);
        float e3 = __expf(LAM * fmaf(l3, rv[s + 3], cv[s + 3]) - mxc);
        sum += (e0 + e1) + (e2 + e3);
        sev = fmaf(e0, v0, sev); sev = fmaf(e1, v1, sev);
        sev = fmaf(e2, v2, sev); sev = fmaf(e3, v3, sev);
        uint2 o;
        o.x = (unsigned)f2bf(e0) | ((unsigned)f2bf(e1) << 16);
        o.y = (unsigned)f2bf(e2) | ((unsigned)f2bf(e3) << 16);
        *(uint2*)(rowp + u * 8) = o;
      }
      sumev[ci * 128 + n] = sev;
      invv[ci * 128 + n] = 1.0f / sum;
    }
  }
  __syncthreads();

  // ---- Phase 3: per-c U = G_c @ e_c (MFMA, A from regs); wn2_u from C-regs --
  {
#pragma unroll
    for (int i = 0; i < 16; i++) regs[i] = {0.f, 0.f, 0.f, 0.f};
#pragma unroll
    for (int ks = 0; ks < KS3; ks++) {
      short8 b2[8];
#pragma unroll
      for (int nt = 0; nt < 8; nt++) {
        const char* p = sm + soff(nt * 16 + m16) + c3 * LS * 2 + ks * 64 + grp * 16;
        union { uint2 h[2]; short8 v; } bb;
        bb.h[0] = *(const uint2*)(p);
        bb.h[1] = *(const uint2*)(p + 8);
        b2[nt] = bb.v;
      }
#pragma unroll
      for (int mi = 0; mi < 2; mi++)
#pragma unroll
        for (int nt = 0; nt < 8; nt++)
          regs[mi * 8 + nt] = __builtin_amdgcn_mfma_f32_16x16x32_bf16(
              g_a[mi][ks], b2[nt], regs[mi * 8 + nt], 0, 0, 0);
    }
    float wp[8];
#pragma unroll
    for (int nt = 0; nt < 8; nt++) wp[nt] = 0.f;
#pragma unroll
    for (int nt = 0; nt < 8; nt++) {
#pragma unroll
      for (int mi = 0; mi < 2; mi++) {
        int sp = (hf * 2 + mi) * 16 + grp * 4;
        uint2 ee = *(const uint2*)(sm + soff(nt * 16 + m16) + (c3 * LS + sp) * 2);
        f32x4 uu = regs[mi * 8 + nt];
        wp[nt] += __uint_as_float(ee.x << 16) * uu[0] +
                  __uint_as_float(ee.x & 0xffff0000u) * uu[1] +
                  __uint_as_float(ee.y << 16) * uu[2] +
                  __uint_as_float(ee.y & 0xffff0000u) * uu[3];
      }
    }
#pragma unroll
    for (int o = 16; o < 64; o <<= 1)
#pragma unroll
      for (int nt = 0; nt < 8; nt++) wp[nt] += __shfl_xor(wp[nt], o);
    if (lane < 16) {
#pragma unroll
      for (int nt = 0; nt < 8; nt++) psum[w * 128 + nt * 16 + lane] = wp[nt];
    }
  }
  __syncthreads();

  // ---- Final: cos + mean over l -> sim ----
  {
    const int p = t >> 5, l0 = t & 31;
    const int cc = p / GQ, qi = p % GQ;
    float sum = 0.f;
#pragma unroll
    for (int li = 0; li < LQ / 32; li++) {
      int n = qi * LQ + l0 + li * 32;
      float nq = qnv[n];
      float inv = invv[cc * 128 + n];
      float w12 = sumev[cc * 128 + n] * inv;
      float wn2u = 0.f;
#pragma unroll
      for (int h = 0; h < WPC; h++) wn2u += psum[(cc * WPC + h) * 128 + n];
      float wn2 = wn2u * inv * inv;
      float denom = fmaxf(nq * sqrtf(fmaxf(wn2, 0.f)), 1e-8f);
      sum += (nq + EPSF) * w12 / denom;
    }
#pragma unroll
    for (int o = 1; o < 32; o <<= 1) sum += __shfl_xor(sum, o);
    if (l0 == 0) sim[(bc * GC + cc) * 128 + bq * GQ + qi] = sum * (1.0f / (float)LQ);
  }
}

// ---------------------------------------------------------------------------
// Loss reductions (unchanged, exact).
// ---------------------------------------------------------------------------
__global__ __launch_bounds__(128) void loss_rows(
    const float* __restrict__ gsim, const float* __restrict__ i2t,
    const float* __restrict__ t2i, float* __restrict__ grow,
    float* __restrict__ gcol, float* __restrict__ lrow) {
  const int i = blockIdx.x, j = threadIdx.x;
  const int B = 128;
  __shared__ float sh[2];
  auto bmax = [&](float v) -> float {
#pragma unroll
    for (int o = 32; o; o >>= 1) v = fmaxf(v, __shfl_down(v, o));
    if ((j & 63) == 0) sh[j >> 6] = v;
    __syncthreads();
    float r = fmaxf(sh[0], sh[1]);
    __syncthreads();
    return r;
  };
  auto bsum = [&](float v) -> float {
#pragma unroll
    for (int o = 32; o; o >>= 1) v += __shfl_down(v, o);
    if ((j & 63) == 0) sh[j >> 6] = v;
    __syncthreads();
    float r = sh[0] + sh[1];
    __syncthreads();
    return r;
  };
  float xr = gsim[i * B + j] * 20.f;
  float xc = gsim[j * B + i] * 20.f;
  float sc = (i2t[i * B + j] + t2i[j * B + i]) * LAM;
  float mr = bmax(xr);
  float lser = mr + logf(bsum(__expf(xr - mr)));
  float mc = bmax(xc);
  float lsec = mc + logf(bsum(__expf(xc - mc)));
  float ml = bmax(sc);
  float lsel = ml + logf(bsum(__expf(sc - ml)));
  float pred = __expf(sc - lsel);
  float logLab = (i == j) ? logf(1.0f + 1e-6f) : logf(1e-6f);
  float tsum = bsum(pred * (sc - lsel - logLab));
  if (j == 0) {
    float d = gsim[i * B + i] * 20.f;
    grow[i] = d - lser;
    gcol[i] = d - lsec;
    lrow[i] = tsum;
  }
}

__global__ __launch_bounds__(128) void loss_final(const float* __restrict__ grow,
                                                  const float* __restrict__ gcol,
                                                  const float* __restrict__ lrow,
                                                  float* __restrict__ out) {
  const int j = threadIdx.x;
  __shared__ float sh[2];
  auto bsum = [&](float v) -> float {
#pragma unroll
    for (int o = 32; o; o >>= 1) v += __shfl_down(v, o);
    if ((j & 63) == 0) sh[j >> 6] = v;
    __syncthreads();
    float r = sh[0] + sh[1];
    __syncthreads();
    return r;
  };
  float a = bsum(grow[j]);
  float b = bsum(gcol[j]);
  float c = bsum(lrow[j]);
  if (j == 0) {
    float gl = -(a / 128.f) - (b / 128.f);
    float ll = c / 128.f;
    out[0] = gl + ll;
    out[1] = gl;
    out[2] = ll;
  }
}

extern "C" void kernel_launch(void* const* d_in, const int* in_sizes, int n_in,
                              void* d_out, int out_size, void* d_ws,
                              size_t ws_size, hipStream_t stream) {
  const float* gsim = (const float*)d_in[0];  // (128,128)
  const float* im = (const float*)d_in[1];    // (128,64,512)
  const float* s = (const float*)d_in[2];     // (128,32,512)
  const float* im_m = (const float*)d_in[3];  // (128,64)
  const float* s_m = (const float*)d_in[5];   // (128,32)
  float* out = (float*)d_out;

  float* ws = (float*)d_ws;
  float* nim = ws;                                         // 8192
  float* ns = ws + 8192;                                   // 4096
  float* i2t = ws + 12288;                                 // 16384
  float* t2i = ws + 28672;                                 // 16384
  float* grow = ws + 45056;                                // 128
  float* gcol = ws + 45184;                                // 128
  float* lrow = ws + 45312;                                // 128
  unsigned short* Gim = (unsigned short*)(ws + 45440);     // 128*64*64 bf16
  unsigned short* Gs = (unsigned short*)(ws + 307584);     // 128*32*32 bf16
  unsigned short* imn = (unsigned short*)(ws + 373120);    // 128*64*512 bf16
  unsigned short* sn = (unsigned short*)(ws + 2470272);    // 128*32*512 bf16

  norm_convert<<<dim3(3072), dim3(256), 0, stream>>>(im, s, nim, ns, imn, sn);
  gram_mfma<64><<<dim3(128), dim3(256), 0, stream>>>(imn, Gim);
  gram_mfma<32><<<dim3(128), dim3(256), 0, stream>>>(sn, Gs);
  // i2t: ctx=images(LS=64,GC=2), qry=captions(LQ=32,GQ=4)
  attn_tile<64, 32, 2, 4><<<dim3(32, 64), dim3(256), 0, stream>>>(
      imn, sn, Gim, ns, im_m, i2t);
  // t2i: ctx=captions(LS=32,GC=4), qry=images(LQ=64,GQ=2)
  attn_tile<32, 64, 4, 2><<<dim3(64, 32), dim3(256), 0, stream>>>(
      sn, imn, Gs, nim, s_m, t2i);
  loss_rows<<<dim3(128), dim3(128), 0, stream>>>(gsim, i2t, t2i, grow, gcol, lrow);
  loss_final<<<dim3(1), dim3(128), 0, stream>>>(grow, gcol, lrow, out);
}